// Round 16
// baseline (25338.759 us; speedup 1.0000x reference)
//
#include <hip/hip_runtime.h>

// LayerNorm-LSTM, S=512 B=64 I=H=512 L=2, all I/O f32, all compute f32.
// (chaotic recurrence: any bf16 => absmax ~1.4 FAIL; f32 deterministic-order
//  noise => ~0.016 PASS. f32 VALU only, fixed reduction orders everywhere.)
//
// R16: XCD-LOCAL architecture. R11-R15 showed tick time (~40us) is pinned by
// cross-XCD coherence-point rounds (~12-15us x3), insensitive to protocol.
// Fix the topology: batch rows decompose the recurrence, so
//   group = 32 WGs on ONE XCD = 16 batch rows x all 2048 gate cols.
//   XCD 0-3 -> layer 0 rows [16g,16g+16); XCD 4-7 -> layer 1 same rows.
//   wh slice [512][64cols] = 128 KB/WG in LDS; wx streamed from local L2
//   (4 MB = L2-resident). h + LN-stats exchanged via agent-scope (sc0,
//   L2-local) atomics: NO MALL trips, NO fences on the critical path.
//   y0 L0->L1: one-way system-scope ring (depth 8), latency hidden by lag.
// Runtime grouping: HW_REG_XCC_ID (verified on MI355X) + per-XCD slot claim;
// grid 256 = #CUs at 1 WG/CU => exactly 32 WGs per XCD (bijection).
// Graph-replay safety: local flags use per-flag BASES read at prologue
// (stale-L2-proof); cross flags are system-scope + memset (reliable).
// Flags/tick (relative): seed=1; slots(t)=3t+2; minv(t)=3t+3; h(t)=3t+4.
// h-wait(t) = 3t+1 (t=0 -> seed). Deterministic f32 everywhere.

#define NTH 256
typedef float f32x4 __attribute__((ext_vector_type(4)));

__device__ __forceinline__ float sigm(float x) { return 1.f / (1.f + __expf(-x)); }
__device__ __forceinline__ float tanh_f(float x) { return 2.f / (1.f + __expf(-2.f * x)) - 1.f; }

// ---- agent scope (XCD-local L2, sc0) ----
__device__ __forceinline__ unsigned agent_ld32(const unsigned* p) {
  return __hip_atomic_load(p, __ATOMIC_RELAXED, __HIP_MEMORY_SCOPE_AGENT);
}
__device__ __forceinline__ void agent_st32(unsigned* p, unsigned v) {
  __hip_atomic_store(p, v, __ATOMIC_RELAXED, __HIP_MEMORY_SCOPE_AGENT);
}
__device__ __forceinline__ unsigned long long agent_ld64(const unsigned long long* p) {
  return __hip_atomic_load(p, __ATOMIC_RELAXED, __HIP_MEMORY_SCOPE_AGENT);
}
__device__ __forceinline__ void agent_st64(unsigned long long* p, unsigned long long v) {
  __hip_atomic_store(p, v, __ATOMIC_RELAXED, __HIP_MEMORY_SCOPE_AGENT);
}
// ---- system scope (MALL) ----
__device__ __forceinline__ unsigned sys_ld32(const unsigned* p) {
  return __hip_atomic_load(p, __ATOMIC_RELAXED, __HIP_MEMORY_SCOPE_SYSTEM);
}
__device__ __forceinline__ void sys_st32(unsigned* p, unsigned v) {
  __hip_atomic_store(p, v, __ATOMIC_RELAXED, __HIP_MEMORY_SCOPE_SYSTEM);
}
__device__ __forceinline__ unsigned long long sys_ld64(const unsigned long long* p) {
  return __hip_atomic_load(p, __ATOMIC_RELAXED, __HIP_MEMORY_SCOPE_SYSTEM);
}

__device__ __forceinline__ unsigned long long pk2(float a, float b) {
  union { float f[2]; unsigned long long u; } x; x.f[0] = a; x.f[1] = b; return x.u;
}
__device__ __forceinline__ float u2f(unsigned u) {
  union { unsigned u; float f; } x; x.u = u; return x.f;
}
__device__ __forceinline__ float lo2(unsigned long long u) {
  union { unsigned long long u; float f[2]; } x; x.u = u; return x.f[0];
}
__device__ __forceinline__ float hi2(unsigned long long u) {
  union { unsigned long long u; float f[2]; } x; x.u = u; return x.f[1];
}

__global__ __launch_bounds__(NTH, 1)
void lstm_pk(const float* __restrict__ inputs, const float* __restrict__ h0,
             const float* __restrict__ c0,
             const float* __restrict__ wx0, const float* __restrict__ wx1,
             const float* __restrict__ wh0, const float* __restrict__ wh1,
             const float* __restrict__ bias, const float* __restrict__ gamma_,
             const float* __restrict__ beta_,
             float* __restrict__ out,
             unsigned* ws_ctr,        // [8] u32 slot-claim counters (memset 0)
             unsigned* lflags,        // [8 grp][64] u32 local flags (memset 0)
             unsigned* y0f,           // [4][16] u32 cross: y0(t) posted (memset)
             unsigned* l1f,           // [4][16] u32 cross: L1 progress (memset)
             unsigned long long* slotbuf,  // [8 grp][32 slice][64 pair] u64
             unsigned long long* minv_g,   // [8 grp][64 pair] u64
             unsigned* h_T,           // [2][4][512 col][16 row] f32-as-u32
             float* __restrict__ y0r) // [4 grp][8 ring][512 col][16 row] f32
{
  extern __shared__ float lds[];
  float* Wlds  = lds;             // [512][64]            32768 f = 128 KB
  float* part  = lds + 32768;     // [4][16][68]           4352 f
  float* gates = lds + 37120;     // [16][64]              1024 f
  float* red   = lds + 38144;     // [16][16][2]            512 f
  float* redsl = lds + 38656;     // [2][32][2]             128 f
  float* minvl = lds + 38784;     // [64][2]                128 f
  unsigned* misc = (unsigned*)(lds + 38912);  // [40] u32 (bases[32], slot, xcc)

  const int tid = threadIdx.x;

  // ---- prologue: XCD id, flag bases, slot claim -------------------------
  unsigned xcc_raw;
  asm volatile("s_getreg_b32 %0, hwreg(20, 0, 4)" : "=s"(xcc_raw));
  const int xcc = (int)(xcc_raw & 7u);
  const int layer = xcc >> 2;
  const int g = xcc & 3;          // row group: rows [16g, 16g+16)
  const int grp8 = xcc;           // 0..7 group index

  unsigned* fl = lflags + grp8 * 64;
  if (tid < 32) misc[tid] = agent_ld32(&fl[tid]);   // per-flag bases
  __syncthreads();
  if (tid == 0) {
    unsigned s0 = __hip_atomic_fetch_add(&ws_ctr[xcc], 1u, __ATOMIC_ACQ_REL,
                                         __HIP_MEMORY_SCOPE_SYSTEM);
    misc[32] = s0 & 31u;
    long guard = 0;
    while (sys_ld32(&ws_ctr[xcc]) < 32u) {          // group closed => all bases read
      if (++guard > (1L << 26)) break;
    }
  }
  __syncthreads();
  const int s = (int)misc[32];    // column slice 0..31: hc [16s, 16s+16)

  const float* Wx = layer ? wx1 : wx0;
  const float* Wh = layer ? wh1 : wh0;

  // ---- stage wh slice: Wlds[k][cq*4+j] = Wh[k][(cq>>2)*512 + 16s + (cq&3)*4 + j]
  for (int u = tid; u < 512 * 16; u += NTH) {
    int k = u >> 4, cq = u & 15;
    int cg = (cq >> 2) * 512 + 16 * s + (cq & 3) * 4;
    *(f32x4*)&Wlds[k * 64 + cq * 4] = *(const f32x4*)&Wh[(size_t)k * 2048 + cg];
  }

  // ---- per-thread constants ----
  // GEMM ids: wavek=tid>>6 (128 k each); ra=lane&3 (rows 4ra..4ra+3); q=lane>>2
  const int wavek = tid >> 6, lane = tid & 63, ra = lane & 3, q = lane >> 2;
  // cell ids: cellr=tid>>4 (row), cj=tid&15 (hc within slice)
  const int cellr = tid >> 4, cj = tid & 15;
  const int hc = 16 * s + cj;
  const int brow = 16 * g + cellr;
  float gam[4], bet[4];
#pragma unroll
  for (int g4 = 0; g4 < 4; ++g4) {
    gam[g4] = gamma_[layer * 2048 + g4 * 512 + hc];
    bet[g4] = beta_[layer * 2048 + g4 * 512 + hc];
  }
  float c_st = c0[layer * 32768 + brow * 512 + hc];
  // merge ids: mr=tid>>4 (row), mq=tid&15 (col quad c4=mq*4)
  const int mr = tid >> 4, mq = tid & 15;
  const int mg4 = mq >> 2, mjq = (mq & 3) * 4;
  f32x4 bias4 = *(const f32x4*)&bias[layer * 2048 + mg4 * 512 + 16 * s + mjq];

  unsigned* hT = h_T + (size_t)(layer * 4 + g) * 8192;   // [512][16] u32
  unsigned long long* sb = slotbuf + (size_t)grp8 * 2048;
  unsigned long long* mg = minv_g + (size_t)grp8 * 64;

  // ---- seed h_T from h0 (this WG's 16 cols x 16 rows); post seed=1 ----
  agent_st32(&hT[hc * 16 + cellr],
             __float_as_uint(h0[layer * 32768 + brow * 512 + hc]));
  __syncthreads();
  if (tid == 0) agent_st32(&fl[s], misc[s] + 1u);

  // ---- helpers (macros via lambdas) ----
  auto wait_local = [&](unsigned target) {   // all 32 group flags >= base+target
    if (tid < 32) {
      unsigned base = misc[tid];
      long guard = 0;
      while ((unsigned)(agent_ld32(&fl[tid]) - base) < target) {
        if (++guard > (1L << 27)) break;
      }
    }
    __syncthreads();
    __atomic_signal_fence(__ATOMIC_ACQUIRE);
  };
  auto post_local = [&](unsigned val) {      // own flag = base + val
    __syncthreads();                         // drains vm/lds of all threads
    if (tid == 0) agent_st32(&fl[s], misc[s] + val);
  };

  f32x4 acc_h[4], acc_x[4];

  for (int t = 0; t < 512; ++t) {
    const unsigned t3 = 3u * (unsigned)t;

    // ========== h-half GEMM (needs h(t-1): flag 3t+1; t=0 -> seed) ==========
    wait_local(t3 + 1u);
#pragma unroll
    for (int i = 0; i < 4; ++i) acc_h[i] = (f32x4){0.f, 0.f, 0.f, 0.f};
    {
      const unsigned long long* h64 = (const unsigned long long*)hT;
#pragma unroll 8
      for (int kk = 0; kk < 128; ++kk) {
        int k = wavek * 128 + kk;
        unsigned long long p0 = agent_ld64(&h64[(k * 16 + 4 * ra) >> 1]);
        unsigned long long p1 = agent_ld64(&h64[((k * 16 + 4 * ra) >> 1) + 1]);
        f32x4 wv = *(const f32x4*)&Wlds[k * 64 + 4 * q];
        acc_h[0] += lo2(p0) * wv;
        acc_h[1] += hi2(p0) * wv;
        acc_h[2] += lo2(p1) * wv;
        acc_h[3] += hi2(p1) * wv;
      }
    }

    // ========== x-half GEMM ==========
#pragma unroll
    for (int i = 0; i < 4; ++i) acc_x[i] = (f32x4){0.f, 0.f, 0.f, 0.f};
    if (layer == 0) {
      const float* xs = inputs + (size_t)t * 32768 + (size_t)(16 * g) * 512;
#pragma unroll 4
      for (int kk = 0; kk < 128; ++kk) {
        int k = wavek * 128 + kk;
        f32x4 wv = *(const f32x4*)&Wx[(size_t)k * 2048 + (q >> 2) * 512 + 16 * s + (q & 3) * 4];
        acc_x[0] += xs[(4 * ra + 0) * 512 + k] * wv;
        acc_x[1] += xs[(4 * ra + 1) * 512 + k] * wv;
        acc_x[2] += xs[(4 * ra + 2) * 512 + k] * wv;
        acc_x[3] += xs[(4 * ra + 3) * 512 + k] * wv;
      }
    } else {
      // y0(t) from L0 group g (cross-XCD, system scope; lag hides latency)
      if (tid == 0) {
        long guard = 0;
        while (sys_ld32(&y0f[g * 16]) < (unsigned)(t + 1)) {
          if (++guard > (1L << 27)) break;
        }
      }
      __syncthreads();
      __atomic_signal_fence(__ATOMIC_ACQUIRE);
      const unsigned long long* y64 = (const unsigned long long*)
          (y0r + ((size_t)(g * 8 + (t & 7)) * 512) * 16);
#pragma unroll 4
      for (int kk = 0; kk < 128; ++kk) {
        int k = wavek * 128 + kk;
        unsigned long long p0 = sys_ld64(&y64[(k * 16 + 4 * ra) >> 1]);
        unsigned long long p1 = sys_ld64(&y64[((k * 16 + 4 * ra) >> 1) + 1]);
        f32x4 wv = *(const f32x4*)&Wx[(size_t)k * 2048 + (q >> 2) * 512 + 16 * s + (q & 3) * 4];
        acc_x[0] += lo2(p0) * wv;
        acc_x[1] += hi2(p0) * wv;
        acc_x[2] += lo2(p1) * wv;
        acc_x[3] += hi2(p1) * wv;
      }
    }

    // ========== K-group partials -> LDS, merge, stats ==========
#pragma unroll
    for (int i = 0; i < 4; ++i)
      *(f32x4*)&part[(wavek * 16 + 4 * ra + i) * 68 + 4 * q] = acc_h[i] + acc_x[i];
    __syncthreads();

    {  // merge 4 K-groups + bias -> gates; 4-col partial -> red
      f32x4 pre = bias4;
#pragma unroll
      for (int w4 = 0; w4 < 4; ++w4)
        pre += *(const f32x4*)&part[(w4 * 16 + mr) * 68 + mq * 4];
      *(f32x4*)&gates[mr * 64 + mq * 4] = pre;
      float s4 = ((pre[0] + pre[1]) + pre[2]) + pre[3];
      float ss4 = ((pre[0] * pre[0] + pre[1] * pre[1]) + pre[2] * pre[2]) + pre[3] * pre[3];
      red[(mr * 16 + mq) * 2 + 0] = s4;
      red[(mr * 16 + mq) * 2 + 1] = ss4;
    }
    __syncthreads();

    if (tid < 64) {  // pair p = tid: row r=tid>>2, gate g4=tid&3 -> slot store
      int r = tid >> 2, g4 = tid & 3;
      float S = 0.f, SS = 0.f;
#pragma unroll
      for (int u = 0; u < 4; ++u) {
        S += red[(r * 16 + g4 * 4 + u) * 2 + 0];
        SS += red[(r * 16 + g4 * 4 + u) * 2 + 1];
      }
      agent_st64(&sb[s * 64 + tid], pk2(S, SS));
    }
    post_local(t3 + 2u);               // slots posted
    wait_local(t3 + 2u);

    // ========== partitioned reduce: WG s owns pairs {2s, 2s+1} ==========
    if (tid < 64) {
      int pi = tid >> 5, sl = tid & 31;
      unsigned long long v = agent_ld64(&sb[sl * 64 + (2 * s + pi)]);
      redsl[(pi * 32 + sl) * 2 + 0] = lo2(v);
      redsl[(pi * 32 + sl) * 2 + 1] = hi2(v);
    }
    __syncthreads();
    if (tid < 2) {
      float S = 0.f, SS = 0.f;
      for (int sl = 0; sl < 32; ++sl) {   // fixed serial order (deterministic)
        S += redsl[(tid * 32 + sl) * 2 + 0];
        SS += redsl[(tid * 32 + sl) * 2 + 1];
      }
      float mu = S * (1.f / 512.f);
      float var = SS * (1.f / 512.f) - mu * mu;
      float inv = rsqrtf(fmaxf(var, 0.f) + 1e-5f);
      agent_st64(&mg[2 * s + tid], pk2(mu, inv));
    }
    post_local(t3 + 3u);               // minv posted
    wait_local(t3 + 3u);

    if (tid < 64) {                    // gather minv -> LDS
      unsigned long long v = agent_ld64(&mg[tid]);
      minvl[tid * 2 + 0] = lo2(v);
      minvl[tid * 2 + 1] = hi2(v);
    }
    // L0 ring backpressure: slot t&7 was read by L1 at its tick t-8
    if (layer == 0 && t >= 8 && tid == 0) {
      long guard = 0;
      while (sys_ld32(&l1f[g * 16]) < (unsigned)(t - 7)) {
        if (++guard > (1L << 27)) break;
      }
    }
    __syncthreads();

    // ========== normalize + cell (thread owns (cellr, hc)) ==========
    {
      float gv[4];
#pragma unroll
      for (int g4 = 0; g4 < 4; ++g4) {
        float pre = gates[cellr * 64 + g4 * 16 + cj];
        gv[g4] = (pre - minvl[(cellr * 4 + g4) * 2]) * minvl[(cellr * 4 + g4) * 2 + 1]
                 * gam[g4] + bet[g4];
      }
      float ig = sigm(gv[0]);
      float fg = sigm(gv[1]);
      float og = sigm(gv[2]);
      float ug = tanh_f(gv[3]);
      c_st = fg * c_st + ig * ug;
      float hv = og * tanh_f(c_st);

      agent_st32(&hT[hc * 16 + cellr], __float_as_uint(hv));
      if (layer == 0) {
        unsigned* yp = (unsigned*)&y0r[((size_t)(g * 8 + (t & 7)) * 512 + hc) * 16 + cellr];
        sys_st32(yp, __float_as_uint(hv));
      } else {
        out[(size_t)t * 32768 + brow * 512 + hc] = hv;   // plain store (host-read)
      }
      if (t == 511) {
        out[16777216 + layer * 32768 + brow * 512 + hc] = hv;     // h_n
        out[16842752 + layer * 32768 + brow * 512 + hc] = c_st;   // c_n
      }
    }
    post_local(t3 + 4u);               // h (and y0) posted
    wait_local(t3 + 4u);

    // cross progress posts (after whole group passed round C)
    if (s == 0 && tid == 0) {
      if (layer == 0) sys_st32(&y0f[g * 16], (unsigned)(t + 1));
      else            sys_st32(&l1f[g * 16], (unsigned)(t + 1));
    }
  }
}

extern "C" void kernel_launch(void* const* d_in, const int* in_sizes, int n_in,
                              void* d_out, int out_size, void* d_ws, size_t ws_size,
                              hipStream_t stream) {
  const float* inputs = (const float*)d_in[0];
  const float* h0 = (const float*)d_in[1];
  const float* c0 = (const float*)d_in[2];
  const float* wx0 = (const float*)d_in[3];
  const float* wx1 = (const float*)d_in[4];
  const float* wh0 = (const float*)d_in[5];
  const float* wh1 = (const float*)d_in[6];
  const float* bias = (const float*)d_in[7];
  const float* gamma_ = (const float*)d_in[8];
  const float* beta_ = (const float*)d_in[9];
  float* out = (float*)d_out;

  char* ws = (char*)d_ws;
  unsigned* ws_ctr = (unsigned*)ws;                      // 32 B
  unsigned* lflags = (unsigned*)(ws + 4096);             // 2 KB
  unsigned* y0f = (unsigned*)(ws + 8192);                // 256 B
  unsigned* l1f = (unsigned*)(ws + 8448);                // 256 B
  unsigned long long* slotbuf = (unsigned long long*)(ws + 16384);   // 128 KB
  unsigned long long* minv_g = (unsigned long long*)(ws + 147456);   // 4 KB
  unsigned* h_T = (unsigned*)(ws + 151552);              // 256 KB
  float* y0r = (float*)(ws + 413696);                    // 1 MB

  const int smem_bytes = 38952 * 4;   // 155808 B
  hipFuncSetAttribute((const void*)lstm_pk,
                      hipFuncAttributeMaxDynamicSharedMemorySize, smem_bytes);
  hipMemsetAsync(ws, 0, 16384, stream);   // ctr + local-flag memory + cross flags

  hipLaunchKernelGGL(lstm_pk, dim3(256), dim3(NTH), smem_bytes, stream,
                     inputs, h0, c0, wx0, wx1, wh0, wh1, bias, gamma_, beta_,
                     out, ws_ctr, lflags, y0f, l1f, slotbuf, minv_g, h_T, y0r);
}

// Round 18
// 20707.584 us; speedup vs baseline: 1.2236x; 1.2236x over previous
//
#include <hip/hip_runtime.h>

// LayerNorm-LSTM, S=512 B=64 I=H=512 L=2, all I/O f32, all compute f32.
// (chaotic recurrence: any bf16 => absmax ~1.4 FAIL; deterministic-f32 order
//  noise => ~0.016 PASS. f32 VALU only, fixed reduction orders.)
//
// R18 = R17 with the replay-state bug fixed: init_k now grid-strides over
// BOTH layers (R17 seeded only layer 0 => timed replays inherited the
// previous replay's final h/c for layer 1 and failed re-validation).
//
// Structure (R17): ZERO custom sync; kernel boundaries are the barrier.
//   Per tick tau (0..512), two stream-ordered launches:
//   - gemm_step: 256 WGs = [layer][w 128]; WG owns 16 gate-cols x 64 rows,
//     W slice (64 KB) in LDS; h-half and L1's x-half read DIRECTLY from
//     transposed ws buffers (h_T, y0_T); L0's x staged via LDS. Writes
//     pre-LN gates+bias to gates_ws.
//   - cell_step: 128 WGs = [layer][row]; R6-proven row-local deterministic
//     LN + cell; writes h_T/y0_T transposed, out, h_n/c_n.
//   L1 lags L0 by one tick -> single-buffer h_T/y0_T race-free by stream
//   ordering alone.

typedef float f32x4 __attribute__((ext_vector_type(4)));

__device__ __forceinline__ float sigm(float x) { return 1.f / (1.f + __expf(-x)); }
__device__ __forceinline__ float tanh_f(float x) { return 2.f / (1.f + __expf(-2.f * x)) - 1.f; }

// one-time: h_T seed (transposed, BOTH layers) + c_ws seed
__global__ void init_k(const float* __restrict__ h0, const float* __restrict__ c0,
                       float* __restrict__ h_T, float* __restrict__ c_ws) {
  const int nthr = gridDim.x * 256;
  for (int i = blockIdx.x * 256 + threadIdx.x; i < 2 * 64 * 512; i += nthr) {
    int l = i >> 15, rem = i & 32767, b = rem >> 9, hc = rem & 511;
    h_T[(l * 512 + hc) * 64 + b] = h0[i];
    c_ws[i] = c0[i];
  }
}

__global__ __launch_bounds__(256)
void gemm_step(const float* __restrict__ inputs,
               const float* __restrict__ wx0, const float* __restrict__ wx1,
               const float* __restrict__ wh0, const float* __restrict__ wh1,
               const float* __restrict__ bias,
               const float* __restrict__ h_T, const float* __restrict__ y0_T,
               float* __restrict__ gates_ws, int tau)
{
  extern __shared__ float lds[];
  float* W_lds = lds;                  // [1024][16]   16384 f = 64 KB
  float* A_lds = lds + 16384;          // [2][128][68] 17408 f = 68 KB (L0 x-stage)
  float* part  = lds + 33792;          // [4][64][17]   4352 f = 17 KB

  const int tid = threadIdx.x;
  const int wg = blockIdx.x;
  const int layer = wg >> 7;
  const int w = wg & 127;              // gate-col slice: hc [4w,4w+4) x 4 gates
  if (layer == 0 ? (tau >= 512) : (tau < 1)) return;
  const int t = layer ? (tau - 1) : tau;

  const int wavet = tid >> 6, lane = tid & 63;
  const int rq = lane & 15;            // row quad -> rows 4rq..4rq+3
  const int gq = lane >> 4;            // gate (col quad)
  const int srow = tid >> 2, sg = tid & 3;

  const float* Wx = layer ? wx1 : wx0;
  const float* Wh = layer ? wh1 : wh0;

  // stage W slice: W_lds[k][g*4+j] = W[k][g*512+4w+j]
  for (int i = 0; i < 16; ++i) {
    int e = tid + i * 256;
    int k = e >> 2, g = e & 3;
    const float* src = (k < 512) ? (Wx + (size_t)k * 2048)
                                 : (Wh + (size_t)(k - 512) * 2048);
    *(f32x4*)&W_lds[k * 16 + g * 4] = *(const f32x4*)(src + g * 512 + 4 * w);
  }
  __syncthreads();

  f32x4 biasr = *(const f32x4*)(bias + layer * 2048 + sg * 512 + 4 * w);
  f32x4 acc[4];
#pragma unroll
  for (int r = 0; r < 4; ++r) acc[r] = (f32x4){0.f, 0.f, 0.f, 0.f};

  // ---- h-half: direct transposed reads (h_T written by prior cell_step)
  {
    const float* hT = h_T + layer * 32768;   // [512][64]
    const int k0 = wavet * 128;
#pragma unroll 8
    for (int kk = 0; kk < 128; ++kk) {
      int k = k0 + kk;
      f32x4 av = *(const f32x4*)&hT[k * 64 + 4 * rq];
      f32x4 wv = *(const f32x4*)&W_lds[(512 + k) * 16 + gq * 4];
      acc[0] += av[0] * wv;
      acc[1] += av[1] * wv;
      acc[2] += av[2] * wv;
      acc[3] += av[3] * wv;
    }
  }

  // ---- x-half
  if (layer == 1) {
    // y0(t) transposed (written by cell_step of tick tau-1)
    const int k0 = wavet * 128;
#pragma unroll 8
    for (int kk = 0; kk < 128; ++kk) {
      int k = k0 + kk;
      f32x4 av = *(const f32x4*)&y0_T[k * 64 + 4 * rq];
      f32x4 wv = *(const f32x4*)&W_lds[k * 16 + gq * 4];
      acc[0] += av[0] * wv;
      acc[1] += av[1] * wv;
      acc[2] += av[2] * wv;
      acc[3] += av[3] * wv;
    }
  } else {
    // row-major inputs: LDS transpose staging, 4 chunks double-buffered
    const float* xsrc = inputs + (size_t)t * 32768;
    const int strow = rq + 16 * wavet;
    f32x4 st[8];
    auto LOADC = [&](int koff) {
      const float* s = xsrc + strow * 512 + koff;
#pragma unroll
      for (int i = 0; i < 8; ++i)
        st[i] = *(const f32x4*)(s + 4 * (gq + 4 * i));
    };
    auto WRITEC = [&](int b) {
      float* dst = A_lds + b * 8704;
#pragma unroll
      for (int i = 0; i < 8; ++i) {
        int kq = gq + 4 * i;
#pragma unroll
        for (int j = 0; j < 4; ++j)
          dst[(4 * kq + j) * 68 + strow] = st[i][j];
      }
    };
    LOADC(0);
    WRITEC(0);
    __syncthreads();
#pragma unroll 1
    for (int i = 0; i < 4; ++i) {
      if (i < 3) LOADC((i + 1) * 128);
      const float* Ab = A_lds + (i & 1) * 8704;
      const int kg = i * 128 + wavet * 32;
#pragma unroll 8
      for (int kk = 0; kk < 32; ++kk) {
        int k = wavet * 32 + kk;
        f32x4 av = *(const f32x4*)&Ab[k * 68 + 4 * rq];
        f32x4 wv = *(const f32x4*)&W_lds[(kg + kk) * 16 + gq * 4];
        acc[0] += av[0] * wv;
        acc[1] += av[1] * wv;
        acc[2] += av[2] * wv;
        acc[3] += av[3] * wv;
      }
      if (i < 3) WRITEC((i + 1) & 1);
      __syncthreads();
    }
  }

  // ---- K-group partials -> LDS -> merged pre-LN gates (+bias) -> global
#pragma unroll
  for (int r = 0; r < 4; ++r)
#pragma unroll
    for (int cc = 0; cc < 4; ++cc)
      part[(wavet * 64 + 4 * rq + r) * 17 + gq * 4 + cc] = acc[r][cc];
  __syncthreads();
  {
    f32x4 pre;
#pragma unroll
    for (int cc = 0; cc < 4; ++cc) {
      float v = biasr[cc];
      v += part[(0 * 64 + srow) * 17 + sg * 4 + cc];
      v += part[(1 * 64 + srow) * 17 + sg * 4 + cc];
      v += part[(2 * 64 + srow) * 17 + sg * 4 + cc];
      v += part[(3 * 64 + srow) * 17 + sg * 4 + cc];
      pre[cc] = v;
    }
    *(f32x4*)&gates_ws[((size_t)layer * 64 + srow) * 2048 + sg * 512 + 4 * w] = pre;
  }
}

__global__ __launch_bounds__(256)
void cell_step(const float* __restrict__ gates_ws,
               const float* __restrict__ gamma_, const float* __restrict__ beta_,
               float* __restrict__ c_ws, float* __restrict__ h_T,
               float* __restrict__ y0_T, float* __restrict__ out, int tau)
{
  __shared__ float sred[512];
  __shared__ float minv[8];
  __shared__ float gnorm[2048];

  const int tid = threadIdx.x;
  const int wgid = blockIdx.x;
  const int l = wgid >> 6, b = wgid & 63;
  if (l == 0 ? (tau >= 512) : (tau < 1)) return;
  const int t = l ? (tau - 1) : tau;

  const float* grow = gates_ws + ((size_t)l * 64 + b) * 2048;
  const int c0i = tid * 8;
  float acc[8];
#pragma unroll
  for (int j = 0; j < 8; ++j) acc[j] = grow[c0i + j];

  // R6-proven deterministic row-local LN stats
  {
    float s = 0.f, ss = 0.f;
#pragma unroll
    for (int j = 0; j < 8; ++j) { s += acc[j]; ss += acc[j] * acc[j]; }
    sred[tid * 2] = s; sred[tid * 2 + 1] = ss;
  }
  __syncthreads();
  if (tid < 4) {
    float S = 0.f, SS = 0.f;
    for (int u = 0; u < 64; ++u) {
      S += sred[(tid * 64 + u) * 2];
      SS += sred[(tid * 64 + u) * 2 + 1];
    }
    float mu = S * (1.f / 512.f);
    float var = SS * (1.f / 512.f) - mu * mu;
    minv[tid * 2] = mu;
    minv[tid * 2 + 1] = rsqrtf(fmaxf(var, 0.f) + 1e-5f);
  }
  __syncthreads();
  {
    int g = tid >> 6;
    float mu = minv[g * 2], inv = minv[g * 2 + 1];
#pragma unroll
    for (int j = 0; j < 8; ++j) {
      int c = c0i + j;
      gnorm[c] = (acc[j] - mu) * inv * gamma_[l * 2048 + c] + beta_[l * 2048 + c];
    }
  }
  __syncthreads();

#pragma unroll
  for (int v = 0; v < 2; ++v) {
    int hc = tid * 2 + v;
    float ig = sigm(gnorm[hc]);
    float fg = sigm(gnorm[512 + hc]);
    float og = sigm(gnorm[1024 + hc]);
    float ug = tanh_f(gnorm[1536 + hc]);
    float cs = fg * c_ws[l * 32768 + b * 512 + hc] + ig * ug;
    float hv = og * tanh_f(cs);
    c_ws[l * 32768 + b * 512 + hc] = cs;
    h_T[(l * 512 + hc) * 64 + b] = hv;       // transposed for next gemm_step
    if (l == 0) y0_T[hc * 64 + b] = hv;      // transposed handoff to L1
    else        out[(size_t)t * 32768 + b * 512 + hc] = hv;
    if (t == 511) {
      out[16777216 + l * 32768 + b * 512 + hc] = hv;   // h_n
      out[16842752 + l * 32768 + b * 512 + hc] = cs;   // c_n
    }
  }
}

extern "C" void kernel_launch(void* const* d_in, const int* in_sizes, int n_in,
                              void* d_out, int out_size, void* d_ws, size_t ws_size,
                              hipStream_t stream) {
  const float* inputs = (const float*)d_in[0];
  const float* h0 = (const float*)d_in[1];
  const float* c0 = (const float*)d_in[2];
  const float* wx0 = (const float*)d_in[3];
  const float* wx1 = (const float*)d_in[4];
  const float* wh0 = (const float*)d_in[5];
  const float* wh1 = (const float*)d_in[6];
  const float* bias = (const float*)d_in[7];
  const float* gamma_ = (const float*)d_in[8];
  const float* beta_ = (const float*)d_in[9];
  float* out = (float*)d_out;

  char* ws = (char*)d_ws;
  float* gates_ws = (float*)ws;                    // [2][64][2048]  1 MB
  float* h_T = (float*)(ws + 1048576);             // [2][512][64]   256 KB
  float* y0_T = (float*)(ws + 1310720);            // [512][64]      128 KB
  float* c_ws = (float*)(ws + 1441792);            // [2][64][512]   256 KB

  const int smem_bytes = 38144 * 4;                // 152576 B
  hipFuncSetAttribute((const void*)gemm_step,
                      hipFuncAttributeMaxDynamicSharedMemorySize, smem_bytes);

  hipLaunchKernelGGL(init_k, dim3(256), dim3(256), 0, stream, h0, c0, h_T, c_ws);

  for (int tau = 0; tau <= 512; ++tau) {
    hipLaunchKernelGGL(gemm_step, dim3(256), dim3(256), smem_bytes, stream,
                       inputs, wx0, wx1, wh0, wh1, bias, h_T, y0_T, gates_ws, tau);
    hipLaunchKernelGGL(cell_step, dim3(128), dim3(256), 0, stream,
                       gates_ws, gamma_, beta_, c_ws, h_T, y0_T, out, tau);
  }
}